// Round 2
// baseline (332.427 us; speedup 1.0000x reference)
//
#include <hip/hip_runtime.h>
#include <hip/hip_fp16.h>
#include <cstdint>
#include <cstddef>

#define B_ 512
#define T_ 256
#define N_ 128
#define H_ 64
#define G_ 256  // 4H

typedef __attribute__((ext_vector_type(8))) short short8;
typedef __attribute__((ext_vector_type(4))) float f32x4;

static __device__ __forceinline__ unsigned short f2bf(float f) {
    union { float f; unsigned int i; } v;
    v.f = f;
    unsigned int x = v.i;
    return (unsigned short)((x + 0x7fffu + ((x >> 16) & 1u)) >> 16);  // RNE
}

// ---------------------------------------------------------------------------
// K1: a[b][n] = softmax_n( sum_t x[b][t][n] * aw2[t] )   (pure f32)
// softmax is shift-invariant => h/c/bias contributions cancel exactly.
// ---------------------------------------------------------------------------
__global__ __launch_bounds__(256) void k_attn(const float* __restrict__ x,
                                              const float* __restrict__ attn_w,
                                              float* __restrict__ a_out) {
    __shared__ float aw[T_];
    __shared__ float red[8][128];
    __shared__ float wred[4];
    const int tid = threadIdx.x;
    const int b = blockIdx.x;

    aw[tid] = attn_w[2 * H_ + tid];
    __syncthreads();

    const int n0 = (tid & 31) << 2;
    const int tg = tid >> 5;
    const float* xb = x + (size_t)b * (T_ * N_);
    float p0 = 0.f, p1 = 0.f, p2 = 0.f, p3 = 0.f;
    for (int t = tg; t < T_; t += 8) {
        float4 v = *(const float4*)(xb + t * N_ + n0);
        float w = aw[t];
        p0 += v.x * w; p1 += v.y * w; p2 += v.z * w; p3 += v.w * w;
    }
    red[tg][n0 + 0] = p0; red[tg][n0 + 1] = p1;
    red[tg][n0 + 2] = p2; red[tg][n0 + 3] = p3;
    __syncthreads();

    float s = 0.f;
    if (tid < 128) {
        #pragma unroll
        for (int g = 0; g < 8; ++g) s += red[g][tid];
    }
    float m = (tid < 128) ? s : -1e30f;
    #pragma unroll
    for (int d = 1; d < 64; d <<= 1) m = fmaxf(m, __shfl_xor(m, d));
    if ((tid & 63) == 0) wred[tid >> 6] = m;
    __syncthreads();
    m = fmaxf(wred[0], wred[1]);
    __syncthreads();
    float e = (tid < 128) ? __expf(s - m) : 0.f;
    float z = e;
    #pragma unroll
    for (int d = 1; d < 64; d <<= 1) z += __shfl_xor(z, d);
    if ((tid & 63) == 0) wred[tid >> 6] = z;
    __syncthreads();
    z = wred[0] + wred[1];
    if (tid < 128) a_out[b * N_ + tid] = e / z;
}

// ---------------------------------------------------------------------------
// K2: iw[r][n] = a[b][n]*x[r][n] (f32, exact)  -> d_out
//     gatesx[r][g] = sum_n iw[r][n]*W_ih[g][n] + b_ih[g]+b_hh[g] (f16) -> ws
// bf16 MFMA 16x16x32 internally. 128 rows/block, 4 subtiles of 32.
// ---------------------------------------------------------------------------
__global__ __launch_bounds__(256) void k_wgemm(const float* __restrict__ x,
                                               const float* __restrict__ a_ws,
                                               const float* __restrict__ W_ih,
                                               const float* __restrict__ b_ih,
                                               const float* __restrict__ b_hh,
                                               float* __restrict__ iw,
                                               _Float16* __restrict__ gatesx) {
    __shared__ unsigned short Wl[G_][136];  // bf16, padded stride
    __shared__ unsigned short Al[32][136];
    __shared__ float bias[G_];
    const int tid = threadIdx.x;
    const int row0 = blockIdx.x * 128;
    const int b = row0 >> 8;  // 128-row tiles never straddle a batch

    for (int q = tid; q < G_ * 32; q += 256) {   // W_ih f32 -> bf16 LDS
        int r = q >> 5, c4 = (q & 31) << 2;
        float4 v = *(const float4*)(W_ih + r * N_ + c4);
        Wl[r][c4 + 0] = f2bf(v.x); Wl[r][c4 + 1] = f2bf(v.y);
        Wl[r][c4 + 2] = f2bf(v.z); Wl[r][c4 + 3] = f2bf(v.w);
    }
    bias[tid] = b_ih[tid] + b_hh[tid];

    const float* ab = a_ws + b * N_;
    const int lane = tid & 63;
    const int lr = lane & 15;
    const int lk = (lane >> 4) << 3;
    const int n0 = (tid >> 6) << 6;
    const int orow = (lane >> 4) << 2;

    for (int st = 0; st < 4; ++st) {
        const int r0 = row0 + st * 32;
        __syncthreads();
        for (int q = tid; q < 32 * 32; q += 256) {
            int r = q >> 5, c4 = (q & 31) << 2;
            size_t off = (size_t)(r0 + r) * N_ + c4;
            float4 v = *(const float4*)(x + off);
            float4 w;
            w.x = ab[c4 + 0] * v.x; w.y = ab[c4 + 1] * v.y;
            w.z = ab[c4 + 2] * v.z; w.w = ab[c4 + 3] * v.w;
            *(float4*)(iw + off) = w;           // output 0 (f32, exact)
            Al[r][c4 + 0] = f2bf(w.x); Al[r][c4 + 1] = f2bf(w.y);
            Al[r][c4 + 2] = f2bf(w.z); Al[r][c4 + 3] = f2bf(w.w);
        }
        __syncthreads();

        f32x4 acc[2][4];
        #pragma unroll
        for (int mt = 0; mt < 2; ++mt)
            #pragma unroll
            for (int nt = 0; nt < 4; ++nt)
                acc[mt][nt] = (f32x4){0.f, 0.f, 0.f, 0.f};

        #pragma unroll
        for (int kk = 0; kk < N_; kk += 32) {
            short8 af0 = *(const short8*)(&Al[lr][kk + lk]);
            short8 af1 = *(const short8*)(&Al[16 + lr][kk + lk]);
            #pragma unroll
            for (int nt = 0; nt < 4; ++nt) {
                short8 bfv = *(const short8*)(&Wl[n0 + nt * 16 + lr][kk + lk]);
                acc[0][nt] = __builtin_amdgcn_mfma_f32_16x16x32_bf16(af0, bfv, acc[0][nt], 0, 0, 0);
                acc[1][nt] = __builtin_amdgcn_mfma_f32_16x16x32_bf16(af1, bfv, acc[1][nt], 0, 0, 0);
            }
        }
        // D: col = n0+nt*16+(lane&15), row = mt*16+(lane>>4)*4+reg
        #pragma unroll
        for (int mt = 0; mt < 2; ++mt) {
            #pragma unroll
            for (int nt = 0; nt < 4; ++nt) {
                int col = n0 + nt * 16 + lr;
                float bs = bias[col];
                #pragma unroll
                for (int rg = 0; rg < 4; ++rg) {
                    int rr = r0 + mt * 16 + orow + rg;
                    gatesx[(size_t)rr * G_ + col] = (_Float16)(acc[mt][nt][rg] + bs);
                }
            }
        }
    }
}

// ---------------------------------------------------------------------------
// K3: LSTM recurrence, 16 batches/block via MFMA. 32 blocks x 256 threads.
// Wave-gate remap: wave w, lane c=(lane&15) owns gate cols g = q*64+16w+c,
// q=0..3  =>  each thread's acc[q][rg] are i,f,g,o for cell
// (brow=(lane>>4)*4+rg, j=16w+c): cell math fully lane-local, zero LDS.
// h double-buffered bf16 in LDS [2][16][72]; one barrier per step.
// ---------------------------------------------------------------------------
__global__ __launch_bounds__(256) void k_rnn(const _Float16* __restrict__ gatesx,
                                             const float* __restrict__ W_hh,
                                             float* __restrict__ enc) {
    __shared__ unsigned short hb[2][16][72];   // bf16, 144B row stride
    const int tid = threadIdx.x;
    const int bg = blockIdx.x;       // batch group of 16
    const int w = tid >> 6;
    const int lane = tid & 63;
    const int c = lane & 15;
    const int rq = lane >> 4;
    const int j = w * 16 + c;        // h-column owned by this thread's cells

    // B-fragments: W_hh[g][k] -> bf16 regs. g = q*64+j, k = kk*32+rq*8+e.
    short8 bfrag[4][2];
    #pragma unroll
    for (int q = 0; q < 4; ++q) {
        int g = q * 64 + j;
        #pragma unroll
        for (int kk = 0; kk < 2; ++kk) {
            const float* src = W_hh + g * H_ + kk * 32 + rq * 8;
            float4 v0 = *(const float4*)(src);
            float4 v1 = *(const float4*)(src + 4);
            union { short8 s; unsigned short u[8]; } pk;
            pk.u[0] = f2bf(v0.x); pk.u[1] = f2bf(v0.y);
            pk.u[2] = f2bf(v0.z); pk.u[3] = f2bf(v0.w);
            pk.u[4] = f2bf(v1.x); pk.u[5] = f2bf(v1.y);
            pk.u[6] = f2bf(v1.z); pk.u[7] = f2bf(v1.w);
            bfrag[q][kk] = pk.s;
        }
    }
    // zero hb[1] (h_{-1} = 0; t=0 reads buf 1)
    {
        unsigned short* p = &hb[0][0][0];
        for (int q = tid; q < 16 * 72; q += 256) p[16 * 72 + q] = 0;
    }
    __syncthreads();

    // gatesx addressing: row r = (bg*16 + brow)*256 + t, col g = q*64 + j
    size_t rowbase[4];
    #pragma unroll
    for (int rg = 0; rg < 4; ++rg)
        rowbase[rg] = ((size_t)(bg * 16 + rq * 4 + rg)) * 65536 + j;  // *T_*G_

    float cs[4] = {0.f, 0.f, 0.f, 0.f};
    float gcur[4][4];
    #pragma unroll
    for (int q = 0; q < 4; ++q)
        #pragma unroll
        for (int rg = 0; rg < 4; ++rg)
            gcur[q][rg] = (float)gatesx[rowbase[rg] + q * 64];   // t = 0

    for (int t = 0; t < T_; ++t) {
        const int rb = (t + 1) & 1, wb = t & 1;
        // prefetch t+1 (clamped; last-iter value unused)
        const int tn = (t + 1 < T_) ? (t + 1) : t;
        _Float16 gn[4][4];
        #pragma unroll
        for (int q = 0; q < 4; ++q)
            #pragma unroll
            for (int rg = 0; rg < 4; ++rg)
                gn[q][rg] = gatesx[rowbase[rg] + (size_t)tn * G_ + q * 64];

        // A fragments: h[brow = lane&15][k], k = kk*32 + rq*8 + e
        short8 a0 = *(const short8*)(&hb[rb][c][rq * 8]);
        short8 a1 = *(const short8*)(&hb[rb][c][32 + rq * 8]);

        f32x4 acc[4];
        #pragma unroll
        for (int q = 0; q < 4; ++q) {
            acc[q] = (f32x4){gcur[q][0], gcur[q][1], gcur[q][2], gcur[q][3]};
            acc[q] = __builtin_amdgcn_mfma_f32_16x16x32_bf16(a0, bfrag[q][0], acc[q], 0, 0, 0);
            acc[q] = __builtin_amdgcn_mfma_f32_16x16x32_bf16(a1, bfrag[q][1], acc[q], 0, 0, 0);
        }

        float hv[4];
        #pragma unroll
        for (int rg = 0; rg < 4; ++rg) {
            float ig = acc[0][rg], fg = acc[1][rg], gg = acc[2][rg], og = acc[3][rg];
            float si = 1.f / (1.f + __expf(-ig));
            float sf = 1.f / (1.f + __expf(-fg));
            float so = 1.f / (1.f + __expf(-og));
            float tg = 1.f - 2.f / (__expf(2.f * gg) + 1.f);
            cs[rg] = sf * cs[rg] + si * tg;
            float tc = 1.f - 2.f / (__expf(2.f * cs[rg]) + 1.f);
            hv[rg] = so * tc;
        }

        // write h_t (bf16) for next step's A; write enc (f32)
        #pragma unroll
        for (int rg = 0; rg < 4; ++rg) {
            hb[wb][rq * 4 + rg][j] = f2bf(hv[rg]);
            enc[((size_t)(bg * 16 + rq * 4 + rg) * T_ + t) * H_ + j] = hv[rg];
        }
        __syncthreads();

        #pragma unroll
        for (int q = 0; q < 4; ++q)
            #pragma unroll
            for (int rg = 0; rg < 4; ++rg)
                gcur[q][rg] = (float)gn[q][rg];
    }
}

extern "C" void kernel_launch(void* const* d_in, const int* in_sizes, int n_in,
                              void* d_out, int out_size, void* d_ws, size_t ws_size,
                              hipStream_t stream) {
    if (n_in < 7 || in_sizes[0] != B_ * T_ * N_) return;

    const float* x    = (const float*)d_in[0];
    const float* aw   = (const float*)d_in[1];
    // d_in[2] (attn_b) provably cancels in the softmax — unused.
    const float* W_ih = (const float*)d_in[3];
    const float* W_hh = (const float*)d_in[4];
    const float* b_ih = (const float*)d_in[5];
    const float* b_hh = (const float*)d_in[6];

    float* iwp = (float*)d_out;                          // (B,T,N) f32
    float* enc = (float*)d_out + (size_t)B_ * T_ * N_;   // (B,T,H) f32

    float* a_ws = (float*)d_ws;                                           // B*N f32
    _Float16* gatesx = (_Float16*)((char*)d_ws + (size_t)B_ * N_ * sizeof(float));
    size_t need = (size_t)B_ * N_ * sizeof(float) + (size_t)B_ * T_ * G_ * sizeof(_Float16);
    if (ws_size < need) return;  // fail loudly (output stays zero) rather than corrupt

    hipLaunchKernelGGL(k_attn, dim3(B_), dim3(256), 0, stream, x, aw, a_ws);
    hipLaunchKernelGGL(k_wgemm, dim3(B_ * T_ / 128), dim3(256), 0, stream,
                       x, a_ws, W_ih, b_ih, b_hh, iwp, gatesx);
    hipLaunchKernelGGL(k_rnn, dim3(B_ / 16), dim3(256), 0, stream, gatesx, W_hh, enc);
}

// Round 3
// 270.566 us; speedup vs baseline: 1.2286x; 1.2286x over previous
//
#include <hip/hip_runtime.h>
#include <hip/hip_fp16.h>
#include <cstdint>
#include <cstddef>

#define B_ 512
#define T_ 256
#define N_ 128
#define H_ 64
#define G_ 256  // 4H

typedef __attribute__((ext_vector_type(8))) short short8;
typedef __attribute__((ext_vector_type(4))) float f32x4;

static __device__ __forceinline__ unsigned short f2bf(float f) {
    union { float f; unsigned int i; } v;
    v.f = f;
    unsigned int x = v.i;
    return (unsigned short)((x + 0x7fffu + ((x >> 16) & 1u)) >> 16);  // RNE
}

// ---------------------------------------------------------------------------
// K1+K2 fused: per-batch block (512 blocks, 256 threads).
// Phase A: a[n] = softmax_n( sum_t x[b][t][n]*aw2[t] )  (kept in LDS)
// Phase B: iw = a*x (f32, exact) -> d_out; gatesx = iw@W_ih^T + bias (f16) -> ws
// LDS 80.9 KB -> 2 blocks/CU.
// ---------------------------------------------------------------------------
__global__ __launch_bounds__(256) void k_awgemm(const float* __restrict__ x,
                                                const float* __restrict__ attn_w,
                                                const float* __restrict__ W_ih,
                                                const float* __restrict__ b_ih,
                                                const float* __restrict__ b_hh,
                                                float* __restrict__ iw,
                                                _Float16* __restrict__ gatesx) {
    __shared__ __align__(16) unsigned short Wl[G_][136];  // bf16 W_ih, padded
    __shared__ __align__(16) unsigned short Al[32][136];  // bf16 wx tile (overlaid: red)
    __shared__ float bias[G_];
    __shared__ float aw_s[T_];
    __shared__ float a_s[N_];
    __shared__ float wred[4];
    const int tid = threadIdx.x;
    const int b = blockIdx.x;

    // ---- stage W_ih (f32 -> bf16), bias, attention weights ----
    for (int q = tid; q < G_ * 32; q += 256) {
        int r = q >> 5, c4 = (q & 31) << 2;
        float4 v = *(const float4*)(W_ih + r * N_ + c4);
        Wl[r][c4 + 0] = f2bf(v.x); Wl[r][c4 + 1] = f2bf(v.y);
        Wl[r][c4 + 2] = f2bf(v.z); Wl[r][c4 + 3] = f2bf(v.w);
    }
    bias[tid] = b_ih[tid] + b_hh[tid];
    aw_s[tid] = attn_w[2 * H_ + tid];
    __syncthreads();

    // ---- Phase A: attention softmax (softmax shift-invariance kills h/c/bias) ----
    float (*red)[128] = (float(*)[128])&Al[0][0];  // overlay (Al unused yet)
    const int n0 = (tid & 31) << 2;
    const int tg = tid >> 5;
    const float* xb = x + (size_t)b * (T_ * N_);
    {
        float p0 = 0.f, p1 = 0.f, p2 = 0.f, p3 = 0.f;
        for (int t = tg; t < T_; t += 8) {
            float4 v = *(const float4*)(xb + t * N_ + n0);
            float w = aw_s[t];
            p0 += v.x * w; p1 += v.y * w; p2 += v.z * w; p3 += v.w * w;
        }
        red[tg][n0 + 0] = p0; red[tg][n0 + 1] = p1;
        red[tg][n0 + 2] = p2; red[tg][n0 + 3] = p3;
    }
    __syncthreads();
    {
        float s = 0.f;
        if (tid < 128) {
            #pragma unroll
            for (int g = 0; g < 8; ++g) s += red[g][tid];
        }
        float m = (tid < 128) ? s : -1e30f;
        #pragma unroll
        for (int d = 1; d < 64; d <<= 1) m = fmaxf(m, __shfl_xor(m, d));
        if ((tid & 63) == 0) wred[tid >> 6] = m;
        __syncthreads();
        m = fmaxf(wred[0], wred[1]);
        __syncthreads();
        float e = (tid < 128) ? __expf(s - m) : 0.f;
        float z = e;
        #pragma unroll
        for (int d = 1; d < 64; d <<= 1) z += __shfl_xor(z, d);
        if ((tid & 63) == 0) wred[tid >> 6] = z;
        __syncthreads();
        z = wred[0] + wred[1];
        if (tid < 128) a_s[tid] = e / z;
    }
    __syncthreads();   // a_s ready; red dead -> Al reusable

    // ---- Phase B: weighting + GEMM (proven MFMA tile) ----
    const int lane = tid & 63;
    const int lr = lane & 15;
    const int lk = (lane >> 4) << 3;
    const int gc0 = (tid >> 6) << 6;     // wave's gate-column base
    const int orow = (lane >> 4) << 2;

    for (int st = 0; st < 8; ++st) {
        const int r0 = b * T_ + st * 32;
        __syncthreads();
        for (int q = tid; q < 32 * 32; q += 256) {
            int r = q >> 5, c4 = (q & 31) << 2;
            size_t off = (size_t)(r0 + r) * N_ + c4;
            float4 v = *(const float4*)(x + off);
            float4 w;
            w.x = a_s[c4 + 0] * v.x; w.y = a_s[c4 + 1] * v.y;
            w.z = a_s[c4 + 2] * v.z; w.w = a_s[c4 + 3] * v.w;
            *(float4*)(iw + off) = w;            // output 0 (f32, exact)
            Al[r][c4 + 0] = f2bf(w.x); Al[r][c4 + 1] = f2bf(w.y);
            Al[r][c4 + 2] = f2bf(w.z); Al[r][c4 + 3] = f2bf(w.w);
        }
        __syncthreads();

        f32x4 acc[2][4];
        #pragma unroll
        for (int mt = 0; mt < 2; ++mt)
            #pragma unroll
            for (int nt = 0; nt < 4; ++nt)
                acc[mt][nt] = (f32x4){0.f, 0.f, 0.f, 0.f};

        #pragma unroll
        for (int kk = 0; kk < N_; kk += 32) {
            short8 af0 = *(const short8*)(&Al[lr][kk + lk]);
            short8 af1 = *(const short8*)(&Al[16 + lr][kk + lk]);
            #pragma unroll
            for (int nt = 0; nt < 4; ++nt) {
                short8 bfv = *(const short8*)(&Wl[gc0 + nt * 16 + lr][kk + lk]);
                acc[0][nt] = __builtin_amdgcn_mfma_f32_16x16x32_bf16(af0, bfv, acc[0][nt], 0, 0, 0);
                acc[1][nt] = __builtin_amdgcn_mfma_f32_16x16x32_bf16(af1, bfv, acc[1][nt], 0, 0, 0);
            }
        }
        // D: col = gc0+nt*16+lr, row = mt*16+(lane>>4)*4+reg
        #pragma unroll
        for (int mt = 0; mt < 2; ++mt) {
            #pragma unroll
            for (int nt = 0; nt < 4; ++nt) {
                int col = gc0 + nt * 16 + lr;
                float bs = bias[col];
                #pragma unroll
                for (int rg = 0; rg < 4; ++rg) {
                    int rr = r0 + mt * 16 + orow + rg;
                    gatesx[(size_t)rr * G_ + col] = (_Float16)(acc[mt][nt][rg] + bs);
                }
            }
        }
    }
}

// ---------------------------------------------------------------------------
// K3: LSTM recurrence, VALU form. 512 blocks (1 batch each), 256 threads.
// Thread g owns gate column g: W_hh[g][:] in 64 VGPRs. h broadcast via
// UNIFORM-address LDS float4 reads (bank-broadcast, conflict-free).
// Cell math on lanes 0..63 only. 2 barriers/step.
// ---------------------------------------------------------------------------
__global__ __launch_bounds__(256) void k_rnn2(const _Float16* __restrict__ gatesx,
                                              const float* __restrict__ W_hh,
                                              float* __restrict__ enc) {
    __shared__ __align__(16) float hb[H_];
    __shared__ float gl[G_];
    const int tid = threadIdx.x;
    const int b = blockIdx.x;

    float wr[H_];
    #pragma unroll
    for (int j = 0; j < H_; j += 4) {
        float4 v = *(const float4*)(W_hh + tid * H_ + j);
        wr[j + 0] = v.x; wr[j + 1] = v.y; wr[j + 2] = v.z; wr[j + 3] = v.w;
    }
    if (tid < H_) hb[tid] = 0.f;
    float c = 0.f;

    const _Float16* gx = gatesx + (size_t)b * T_ * G_;
    float gcur = (float)gx[tid];   // t = 0
    __syncthreads();

    for (int t = 0; t < T_; ++t) {
        // prefetch next step's gate input (coalesced 512B per wave-pair)
        _Float16 gn = gx[(size_t)(t + 1 < T_ ? t + 1 : t) * G_ + tid];

        float a0 = gcur, a1 = 0.f, a2 = 0.f, a3 = 0.f;
        const float4* h4 = (const float4*)hb;
        #pragma unroll
        for (int jj = 0; jj < 16; ++jj) {
            float4 hv = h4[jj];                 // uniform address -> broadcast
            a0 += hv.x * wr[4 * jj + 0];
            a1 += hv.y * wr[4 * jj + 1];
            a2 += hv.z * wr[4 * jj + 2];
            a3 += hv.w * wr[4 * jj + 3];
        }
        gl[tid] = (a0 + a1) + (a2 + a3);
        __syncthreads();

        if (tid < H_) {
            float ig = gl[tid], fg = gl[H_ + tid], gg = gl[2 * H_ + tid], og = gl[3 * H_ + tid];
            float si = 1.f / (1.f + __expf(-ig));
            float sf = 1.f / (1.f + __expf(-fg));
            float so = 1.f / (1.f + __expf(-og));
            float tg = 1.f - 2.f / (__expf(2.f * gg) + 1.f);   // tanh
            c = sf * c + si * tg;
            float tc = 1.f - 2.f / (__expf(2.f * c) + 1.f);    // tanh
            float h = so * tc;
            hb[tid] = h;
            enc[((size_t)b * T_ + t) * H_ + tid] = h;
        }
        __syncthreads();
        gcur = (float)gn;
    }
}

extern "C" void kernel_launch(void* const* d_in, const int* in_sizes, int n_in,
                              void* d_out, int out_size, void* d_ws, size_t ws_size,
                              hipStream_t stream) {
    if (n_in < 7 || in_sizes[0] != B_ * T_ * N_) return;

    const float* x    = (const float*)d_in[0];
    const float* aw   = (const float*)d_in[1];
    // d_in[2] (attn_b) provably cancels in the softmax — unused.
    const float* W_ih = (const float*)d_in[3];
    const float* W_hh = (const float*)d_in[4];
    const float* b_ih = (const float*)d_in[5];
    const float* b_hh = (const float*)d_in[6];

    float* iwp = (float*)d_out;                          // (B,T,N) f32
    float* enc = (float*)d_out + (size_t)B_ * T_ * N_;   // (B,T,H) f32

    _Float16* gatesx = (_Float16*)d_ws;                  // B*T*G f16
    size_t need = (size_t)B_ * T_ * G_ * sizeof(_Float16);
    if (ws_size < need) return;  // fail loudly rather than corrupt

    hipLaunchKernelGGL(k_awgemm, dim3(B_), dim3(256), 0, stream,
                       x, aw, W_ih, b_ih, b_hh, iwp, gatesx);
    hipLaunchKernelGGL(k_rnn2, dim3(B_), dim3(256), 0, stream, gatesx, W_hh, enc);
}